// Round 4
// baseline (12906.535 us; speedup 1.0000x reference)
//
#include <hip/hip_runtime.h>
#include <stdint.h>

#define NROWS  8192
#define DMODEL 768
#define DSAE   24576
#define TOPK   64

// =================== Kernel 1: pre = x @ W_enc + b_enc (fp32) ===================
// 128x128 tile, BK=16, 256 threads, 8x8 microtile in 4+4 split (conflict-free
// ds_read_b128), double-buffered LDS with register prefetch, 1 barrier/K-tile.
#define BM 128
#define BN 128
#define BK 16
#define APAD 132   // transposed A-store: 2-way write conflict only (free per m136)

__global__ __launch_bounds__(256, 4)
void gemm_enc(const float* __restrict__ x, const float* __restrict__ W,
              const float* __restrict__ bias, float* __restrict__ pre)
{
    __shared__ float As[2][BK][APAD];   // As[b][k][m] = x[bm+m][kt+k]
    __shared__ float Bs[2][BK][BN];     // Bs[b][k][n] = W[kt+k][bn+n]

    const int tid = threadIdx.x;
    const int bm = blockIdx.y * BM;
    const int bn = blockIdx.x * BN;
    const int ty = tid >> 4;         // 0..15
    const int tx = tid & 15;         // 0..15

    float acc[8][8];
    #pragma unroll
    for (int i = 0; i < 8; ++i)
        #pragma unroll
        for (int j = 0; j < 8; ++j) acc[i][j] = 0.f;

    // staging assignments
    const int am  = tid >> 2;          // A: tile row (and +64)
    const int akq = (tid & 3) * 4;     // A: k offset (float4 along k)
    const int bkr = tid >> 5;          // B: k row (and +8)
    const int bnq = (tid & 31) * 4;    // B: n offset (float4 along n)

    const float* pA0 = x + (size_t)(bm + am) * DMODEL + akq;
    const float* pA1 = x + (size_t)(bm + am + 64) * DMODEL + akq;
    const float* pB0 = W + (size_t)bkr * DSAE + bn + bnq;
    const float* pB1 = W + (size_t)(bkr + 8) * DSAE + bn + bnq;

    // prologue: stage tile 0 into buffer 0
    float4 ra0 = *(const float4*)(pA0);
    float4 ra1 = *(const float4*)(pA1);
    float4 rb0 = *(const float4*)(pB0);
    float4 rb1 = *(const float4*)(pB1);
    As[0][akq + 0][am] = ra0.x;  As[0][akq + 1][am] = ra0.y;
    As[0][akq + 2][am] = ra0.z;  As[0][akq + 3][am] = ra0.w;
    As[0][akq + 0][am + 64] = ra1.x;  As[0][akq + 1][am + 64] = ra1.y;
    As[0][akq + 2][am + 64] = ra1.z;  As[0][akq + 3][am + 64] = ra1.w;
    *(float4*)(&Bs[0][bkr][bnq])     = rb0;
    *(float4*)(&Bs[0][bkr + 8][bnq]) = rb1;
    __syncthreads();

    int cur = 0;
    for (int kt = 0; kt < DMODEL; kt += BK) {
        const bool has_next = (kt + BK) < DMODEL;
        if (has_next) {   // issue next-tile global loads early (latency hides under FMA)
            ra0 = *(const float4*)(pA0 + kt + BK);
            ra1 = *(const float4*)(pA1 + kt + BK);
            rb0 = *(const float4*)(pB0 + (size_t)(kt + BK) * DSAE);
            rb1 = *(const float4*)(pB1 + (size_t)(kt + BK) * DSAE);
        }
        #pragma unroll
        for (int k = 0; k < BK; ++k) {
            float4 av0 = *(const float4*)(&As[cur][k][ty * 4]);
            float4 av1 = *(const float4*)(&As[cur][k][64 + ty * 4]);
            float4 bv0 = *(const float4*)(&Bs[cur][k][tx * 4]);
            float4 bv1 = *(const float4*)(&Bs[cur][k][64 + tx * 4]);
            const float a[8] = {av0.x, av0.y, av0.z, av0.w, av1.x, av1.y, av1.z, av1.w};
            const float b[8] = {bv0.x, bv0.y, bv0.z, bv0.w, bv1.x, bv1.y, bv1.z, bv1.w};
            #pragma unroll
            for (int i = 0; i < 8; ++i)
                #pragma unroll
                for (int j = 0; j < 8; ++j)
                    acc[i][j] += a[i] * b[j];
        }
        if (has_next) {
            const int nb = cur ^ 1;
            As[nb][akq + 0][am] = ra0.x;  As[nb][akq + 1][am] = ra0.y;
            As[nb][akq + 2][am] = ra0.z;  As[nb][akq + 3][am] = ra0.w;
            As[nb][akq + 0][am + 64] = ra1.x;  As[nb][akq + 1][am + 64] = ra1.y;
            As[nb][akq + 2][am + 64] = ra1.z;  As[nb][akq + 3][am + 64] = ra1.w;
            *(float4*)(&Bs[nb][bkr][bnq])     = rb0;
            *(float4*)(&Bs[nb][bkr + 8][bnq]) = rb1;
            __syncthreads();
            cur = nb;
        }
    }

    // epilogue: bias + store (cols tx*4 and 64+tx*4; rows ty*4+i and 64+ty*4+i)
    float4 be0 = *(const float4*)(bias + bn + tx * 4);
    float4 be1 = *(const float4*)(bias + bn + 64 + tx * 4);
    #pragma unroll
    for (int half = 0; half < 2; ++half) {
        #pragma unroll
        for (int i = 0; i < 4; ++i) {
            const int r = bm + half * 64 + ty * 4 + i;
            const int ai = half * 4 + i;
            float* dst = pre + (size_t)r * DSAE + bn;
            *(float4*)(dst + tx * 4) = make_float4(
                acc[ai][0] + be0.x, acc[ai][1] + be0.y,
                acc[ai][2] + be0.z, acc[ai][3] + be0.w);
            *(float4*)(dst + 64 + tx * 4) = make_float4(
                acc[ai][4] + be1.x, acc[ai][5] + be1.y,
                acc[ai][6] + be1.z, acc[ai][7] + be1.w);
        }
    }
}

// =================== Kernel 2: per-row top-64 select + sparsify + decode ===================
#define NT2 512
#define CAP 4096   // candidate capacity; E[cnt]=1917, sd=42 -> 50 sigma headroom

__device__ __forceinline__ unsigned sortable(float f) {
    unsigned u = __float_as_uint(f);
    return u ^ ((u & 0x80000000u) ? 0xFFFFFFFFu : 0x80000000u);
}

__global__ __launch_bounds__(NT2)
void topk_decode(float* __restrict__ lat, const float* __restrict__ Wd,
                 float* __restrict__ out)
{
    const int row = blockIdx.x;
    const int tid = threadIdx.x;
    float* rowp = lat + (size_t)row * DSAE;

    __shared__ unsigned cand_u[CAP];
    __shared__ int      cand_i[CAP];
    __shared__ int hist[256];
    __shared__ int s_cnt, s_bucket, s_krem, s_total_eq, s_cutoff;
    __shared__ float sel_v[TOPK];
    __shared__ int   sel_j[TOPK];
    __shared__ int   sel_cnt;

    // ---- Phase A: one-pass candidate collection (floor 2.0f = sortable 0xC0000000)
    if (tid == 0) s_cnt = 0;
    __syncthreads();
    for (int i4 = tid; i4 < DSAE / 4; i4 += NT2) {
        float4 v = *(const float4*)(rowp + i4 * 4);
        const float vv[4] = {v.x, v.y, v.z, v.w};
        #pragma unroll
        for (int c = 0; c < 4; ++c) {
            unsigned u = sortable(vv[c]);
            if (u >= 0xC0000000u) {
                int s = atomicAdd(&s_cnt, 1);
                if (s < CAP) { cand_u[s] = u; cand_i[s] = i4 * 4 + c; }
            }
        }
    }
    __syncthreads();
    const int n = s_cnt;
    const bool fast = (n >= TOPK && n <= CAP);

    unsigned T;
    int need_eq, total_eq;

    if (fast) {
        // ---- Phase B (fast): radix-select top-64 among n LDS candidates
        unsigned pbase = 0;
        int k_rem = TOPK;
        #pragma unroll 1
        for (int pass = 0; pass < 4; ++pass) {
            const int shift = 24 - 8 * pass;
            const unsigned mask = pass ? (0xFFFFFFFFu << (32 - 8 * pass)) : 0u;
            if (tid < 256) hist[tid] = 0;
            __syncthreads();
            for (int i = tid; i < n; i += NT2) {
                unsigned u = cand_u[i];
                if ((u & mask) == pbase) atomicAdd(&hist[(u >> shift) & 255], 1);
            }
            __syncthreads();
            if (tid == 0) {
                int acc = 0, b = 255;
                for (; b >= 0; --b) {
                    int h = hist[b];
                    if (acc + h >= k_rem) break;
                    acc += h;
                }
                s_bucket = b;
                s_krem = k_rem - acc;
                s_total_eq = hist[b];
            }
            __syncthreads();
            pbase |= ((unsigned)s_bucket) << shift;
            k_rem = s_krem;
            __syncthreads();
        }
        T = pbase; need_eq = k_rem; total_eq = s_total_eq;
    } else {
        // ---- Phase B (fallback): 4-pass radix over the full global row
        unsigned pbase = 0;
        int k_rem = TOPK;
        #pragma unroll 1
        for (int pass = 0; pass < 4; ++pass) {
            const int shift = 24 - 8 * pass;
            const unsigned mask = pass ? (0xFFFFFFFFu << (32 - 8 * pass)) : 0u;
            if (tid < 256) hist[tid] = 0;
            __syncthreads();
            for (int i = tid; i < DSAE; i += NT2) {
                unsigned u = sortable(rowp[i]);
                if ((u & mask) == pbase) atomicAdd(&hist[(u >> shift) & 255], 1);
            }
            __syncthreads();
            if (tid == 0) {
                int acc = 0, b = 255;
                for (; b >= 0; --b) {
                    int h = hist[b];
                    if (acc + h >= k_rem) break;
                    acc += h;
                }
                s_bucket = b;
                s_krem = k_rem - acc;
                s_total_eq = hist[b];
            }
            __syncthreads();
            pbase |= ((unsigned)s_bucket) << shift;
            k_rem = s_krem;
            __syncthreads();
        }
        T = pbase; need_eq = k_rem; total_eq = s_total_eq;
    }

    // ---- cutoff for exact ties at T (jax.lax.top_k keeps lowest indices)
    if (tid == 0) {
        s_cutoff = DSAE;
        if (total_eq != need_eq) {
            int last = -1;
            for (int r = 0; r < need_eq; ++r) {         // repeated-min (tie path ~never taken)
                int best = DSAE;
                if (fast) {
                    for (int i = 0; i < n; ++i)
                        if (cand_u[i] == T && cand_i[i] > last && cand_i[i] < best) best = cand_i[i];
                } else {
                    for (int i = 0; i < DSAE; ++i)
                        if (sortable(rowp[i]) == T && i > last && i < best) best = i;
                }
                last = best;
            }
            s_cutoff = last;
        }
        sel_cnt = 0;
    }
    __syncthreads();
    const int cutoff = s_cutoff;

    // ---- collect the 64 selected (j, v)
    if (fast) {
        for (int i = tid; i < n; i += NT2) {
            unsigned u = cand_u[i];
            int j = cand_i[i];
            if (u > T || (u == T && j <= cutoff)) {
                int s = atomicAdd(&sel_cnt, 1);
                if (s < TOPK) { sel_j[s] = j; sel_v[s] = rowp[j]; }
            }
        }
    } else {
        for (int i = tid; i < DSAE; i += NT2) {
            float v = rowp[i];
            unsigned u = sortable(v);
            if (u > T || (u == T && i <= cutoff)) {
                int s = atomicAdd(&sel_cnt, 1);
                if (s < TOPK) { sel_j[s] = i; sel_v[s] = v; }
            }
        }
    }
    __syncthreads();

    // ---- zero the row, then scatter the selected values back
    for (int i4 = tid; i4 < DSAE / 4; i4 += NT2)
        *(float4*)(rowp + i4 * 4) = make_float4(0.f, 0.f, 0.f, 0.f);
    __syncthreads();
    if (tid < TOPK) rowp[sel_j[tid]] = sel_v[tid];
    __syncthreads();

    // ---- sparse decode: out[row, :] = sum_s v_s * W_dec[j_s, :]
    float a0 = 0.f, a1 = 0.f;
    #pragma unroll 8
    for (int s = 0; s < TOPK; ++s) {
        const float v = sel_v[s];
        const float* wd = Wd + (size_t)sel_j[s] * DMODEL;
        a0 += v * wd[tid];
        if (tid < 256) a1 += v * wd[512 + tid];
    }
    out[(size_t)row * DMODEL + tid] = a0;
    if (tid < 256) out[(size_t)row * DMODEL + 512 + tid] = a1;
}

// =================== launch ===================
extern "C" void kernel_launch(void* const* d_in, const int* in_sizes, int n_in,
                              void* d_out, int out_size, void* d_ws, size_t ws_size,
                              hipStream_t stream) {
    const float* x     = (const float*)d_in[0];
    const float* W_enc = (const float*)d_in[1];
    const float* b_enc = (const float*)d_in[2];
    const float* W_dec = (const float*)d_in[3];
    float* out = (float*)d_out;
    float* lat = out + (size_t)NROWS * DMODEL;   // latents region of d_out

    dim3 g1(DSAE / BN, NROWS / BM);   // (192, 64)
    gemm_enc<<<g1, 256, 0, stream>>>(x, W_enc, b_enc, lat);
    topk_decode<<<NROWS, NT2, 0, stream>>>(lat, W_dec, out);
}

// Round 5
// 4839.602 us; speedup vs baseline: 2.6669x; 2.6669x over previous
//
#include <hip/hip_runtime.h>
#include <stdint.h>

#define NROWS  8192
#define DMODEL 768
#define DSAE   24576
#define TOPK   64

// =================== Kernel 1: pre = x @ W_enc + b_enc (fp32) ===================
// Round-2 structure (single buffer, 2 barriers/K-tile, no min-wave bound — that
// variant measured 0 scratch spill, 82% VALUBusy). Sole change vs R2: 8x8
// microtile in 4+4 split so Bs ds_read_b128 spans all 32 banks (conflict-free).
#define BM 128
#define BN 128
#define BK 16
#define APAD 132   // transposed A-store: 2-way write conflict only (free per m136)

__global__ __launch_bounds__(256)
void gemm_enc(const float* __restrict__ x, const float* __restrict__ W,
              const float* __restrict__ bias, float* __restrict__ pre)
{
    __shared__ float As[BK][APAD];   // As[k][m] = x[bm+m][kt+k]
    __shared__ float Bs[BK][BN];     // Bs[k][n] = W[kt+k][bn+n]

    const int tid = threadIdx.x;
    const int bm = blockIdx.y * BM;
    const int bn = blockIdx.x * BN;
    const int ty = tid >> 4;         // 0..15
    const int tx = tid & 15;         // 0..15

    float acc[8][8];
    #pragma unroll
    for (int i = 0; i < 8; ++i)
        #pragma unroll
        for (int j = 0; j < 8; ++j) acc[i][j] = 0.f;

    const int am  = tid >> 2;          // A: tile row (l=0), +64 for l=1
    const int akq = (tid & 3) * 4;     // A: k offset (float4 along k)
    const int bk  = tid >> 5;          // B: k row (l=0), +8 for l=1
    const int bnq = (tid & 31) * 4;    // B: n offset (float4 along n)

    for (int kt = 0; kt < DMODEL; kt += BK) {
        #pragma unroll
        for (int l = 0; l < 2; ++l) {
            const int m = am + l * 64;
            float4 av = *(const float4*)(x + (size_t)(bm + m) * DMODEL + kt + akq);
            As[akq + 0][m] = av.x;
            As[akq + 1][m] = av.y;
            As[akq + 2][m] = av.z;
            As[akq + 3][m] = av.w;
            const int k = bk + l * 8;
            *(float4*)(&Bs[k][bnq]) = *(const float4*)(W + (size_t)(kt + k) * DSAE + bn + bnq);
        }
        __syncthreads();
        #pragma unroll
        for (int k = 0; k < BK; ++k) {
            float4 av0 = *(const float4*)(&As[k][ty * 4]);         // rows ty*4..+3
            float4 av1 = *(const float4*)(&As[k][64 + ty * 4]);    // rows 64+ty*4..+3
            float4 bv0 = *(const float4*)(&Bs[k][tx * 4]);         // cols tx*4..+3
            float4 bv1 = *(const float4*)(&Bs[k][64 + tx * 4]);    // cols 64+tx*4..+3
            const float a[8] = {av0.x, av0.y, av0.z, av0.w, av1.x, av1.y, av1.z, av1.w};
            const float b[8] = {bv0.x, bv0.y, bv0.z, bv0.w, bv1.x, bv1.y, bv1.z, bv1.w};
            #pragma unroll
            for (int i = 0; i < 8; ++i)
                #pragma unroll
                for (int j = 0; j < 8; ++j)
                    acc[i][j] += a[i] * b[j];
        }
        __syncthreads();
    }

    // epilogue: bias + store (rows {ty*4+i, 64+ty*4+i}, cols {tx*4.., 64+tx*4..})
    float4 be0 = *(const float4*)(bias + bn + tx * 4);
    float4 be1 = *(const float4*)(bias + bn + 64 + tx * 4);
    #pragma unroll
    for (int half = 0; half < 2; ++half) {
        #pragma unroll
        for (int i = 0; i < 4; ++i) {
            const int r = bm + half * 64 + ty * 4 + i;
            const int ai = half * 4 + i;
            float* dst = pre + (size_t)r * DSAE + bn;
            *(float4*)(dst + tx * 4) = make_float4(
                acc[ai][0] + be0.x, acc[ai][1] + be0.y,
                acc[ai][2] + be0.z, acc[ai][3] + be0.w);
            *(float4*)(dst + 64 + tx * 4) = make_float4(
                acc[ai][4] + be1.x, acc[ai][5] + be1.y,
                acc[ai][6] + be1.z, acc[ai][7] + be1.w);
        }
    }
}

// =================== Kernel 2: per-row top-64 select + sparsify + decode ===================
#define NT2 512
#define CAP 4096   // candidate capacity; E[cnt]=1917, sd=42 -> 50 sigma headroom

__device__ __forceinline__ unsigned sortable(float f) {
    unsigned u = __float_as_uint(f);
    return u ^ ((u & 0x80000000u) ? 0xFFFFFFFFu : 0x80000000u);
}

__global__ __launch_bounds__(NT2)
void topk_decode(float* __restrict__ lat, const float* __restrict__ Wd,
                 float* __restrict__ out)
{
    const int row = blockIdx.x;
    const int tid = threadIdx.x;
    float* rowp = lat + (size_t)row * DSAE;

    __shared__ unsigned cand_u[CAP];
    __shared__ int      cand_i[CAP];
    __shared__ int hist[256];
    __shared__ int s_cnt, s_bucket, s_krem, s_total_eq, s_cutoff;
    __shared__ float sel_v[TOPK];
    __shared__ int   sel_j[TOPK];
    __shared__ int   sel_cnt;

    // ---- Phase A: one-pass candidate collection (floor 2.0f = sortable 0xC0000000)
    if (tid == 0) s_cnt = 0;
    __syncthreads();
    for (int i4 = tid; i4 < DSAE / 4; i4 += NT2) {
        float4 v = *(const float4*)(rowp + i4 * 4);
        const float vv[4] = {v.x, v.y, v.z, v.w};
        #pragma unroll
        for (int c = 0; c < 4; ++c) {
            unsigned u = sortable(vv[c]);
            if (u >= 0xC0000000u) {
                int s = atomicAdd(&s_cnt, 1);
                if (s < CAP) { cand_u[s] = u; cand_i[s] = i4 * 4 + c; }
            }
        }
    }
    __syncthreads();
    const int n = s_cnt;
    const bool fast = (n >= TOPK && n <= CAP);

    unsigned T;
    int need_eq, total_eq;

    if (fast) {
        // ---- Phase B (fast): radix-select top-64 among n LDS candidates
        unsigned pbase = 0;
        int k_rem = TOPK;
        #pragma unroll 1
        for (int pass = 0; pass < 4; ++pass) {
            const int shift = 24 - 8 * pass;
            const unsigned mask = pass ? (0xFFFFFFFFu << (32 - 8 * pass)) : 0u;
            if (tid < 256) hist[tid] = 0;
            __syncthreads();
            for (int i = tid; i < n; i += NT2) {
                unsigned u = cand_u[i];
                if ((u & mask) == pbase) atomicAdd(&hist[(u >> shift) & 255], 1);
            }
            __syncthreads();
            if (tid == 0) {
                int acc = 0, b = 255;
                for (; b >= 0; --b) {
                    int h = hist[b];
                    if (acc + h >= k_rem) break;
                    acc += h;
                }
                s_bucket = b;
                s_krem = k_rem - acc;
                s_total_eq = hist[b];
            }
            __syncthreads();
            pbase |= ((unsigned)s_bucket) << shift;
            k_rem = s_krem;
            __syncthreads();
        }
        T = pbase; need_eq = k_rem; total_eq = s_total_eq;
    } else {
        // ---- Phase B (fallback): 4-pass radix over the full global row
        unsigned pbase = 0;
        int k_rem = TOPK;
        #pragma unroll 1
        for (int pass = 0; pass < 4; ++pass) {
            const int shift = 24 - 8 * pass;
            const unsigned mask = pass ? (0xFFFFFFFFu << (32 - 8 * pass)) : 0u;
            if (tid < 256) hist[tid] = 0;
            __syncthreads();
            for (int i = tid; i < DSAE; i += NT2) {
                unsigned u = sortable(rowp[i]);
                if ((u & mask) == pbase) atomicAdd(&hist[(u >> shift) & 255], 1);
            }
            __syncthreads();
            if (tid == 0) {
                int acc = 0, b = 255;
                for (; b >= 0; --b) {
                    int h = hist[b];
                    if (acc + h >= k_rem) break;
                    acc += h;
                }
                s_bucket = b;
                s_krem = k_rem - acc;
                s_total_eq = hist[b];
            }
            __syncthreads();
            pbase |= ((unsigned)s_bucket) << shift;
            k_rem = s_krem;
            __syncthreads();
        }
        T = pbase; need_eq = k_rem; total_eq = s_total_eq;
    }

    // ---- cutoff for exact ties at T (jax.lax.top_k keeps lowest indices)
    if (tid == 0) {
        s_cutoff = DSAE;
        if (total_eq != need_eq) {
            int last = -1;
            for (int r = 0; r < need_eq; ++r) {         // repeated-min (tie path ~never taken)
                int best = DSAE;
                if (fast) {
                    for (int i = 0; i < n; ++i)
                        if (cand_u[i] == T && cand_i[i] > last && cand_i[i] < best) best = cand_i[i];
                } else {
                    for (int i = 0; i < DSAE; ++i)
                        if (sortable(rowp[i]) == T && i > last && i < best) best = i;
                }
                last = best;
            }
            s_cutoff = last;
        }
        sel_cnt = 0;
    }
    __syncthreads();
    const int cutoff = s_cutoff;

    // ---- collect the 64 selected (j, v)
    if (fast) {
        for (int i = tid; i < n; i += NT2) {
            unsigned u = cand_u[i];
            int j = cand_i[i];
            if (u > T || (u == T && j <= cutoff)) {
                int s = atomicAdd(&sel_cnt, 1);
                if (s < TOPK) { sel_j[s] = j; sel_v[s] = rowp[j]; }
            }
        }
    } else {
        for (int i = tid; i < DSAE; i += NT2) {
            float v = rowp[i];
            unsigned u = sortable(v);
            if (u > T || (u == T && i <= cutoff)) {
                int s = atomicAdd(&sel_cnt, 1);
                if (s < TOPK) { sel_j[s] = i; sel_v[s] = v; }
            }
        }
    }
    __syncthreads();

    // ---- zero the row, then scatter the selected values back
    for (int i4 = tid; i4 < DSAE / 4; i4 += NT2)
        *(float4*)(rowp + i4 * 4) = make_float4(0.f, 0.f, 0.f, 0.f);
    __syncthreads();
    if (tid < TOPK) rowp[sel_j[tid]] = sel_v[tid];
    __syncthreads();

    // ---- sparse decode: out[row, :] = sum_s v_s * W_dec[j_s, :]
    float a0 = 0.f, a1 = 0.f;
    #pragma unroll 8
    for (int s = 0; s < TOPK; ++s) {
        const float v = sel_v[s];
        const float* wd = Wd + (size_t)sel_j[s] * DMODEL;
        a0 += v * wd[tid];
        if (tid < 256) a1 += v * wd[512 + tid];
    }
    out[(size_t)row * DMODEL + tid] = a0;
    if (tid < 256) out[(size_t)row * DMODEL + 512 + tid] = a1;
}

// =================== launch ===================
extern "C" void kernel_launch(void* const* d_in, const int* in_sizes, int n_in,
                              void* d_out, int out_size, void* d_ws, size_t ws_size,
                              hipStream_t stream) {
    const float* x     = (const float*)d_in[0];
    const float* W_enc = (const float*)d_in[1];
    const float* b_enc = (const float*)d_in[2];
    const float* W_dec = (const float*)d_in[3];
    float* out = (float*)d_out;
    float* lat = out + (size_t)NROWS * DMODEL;   // latents region of d_out

    dim3 g1(DSAE / BN, NROWS / BM);   // (192, 64)
    gemm_enc<<<g1, 256, 0, stream>>>(x, W_enc, b_enc, lat);
    topk_decode<<<NROWS, NT2, 0, stream>>>(lat, W_dec, out);
}

// Round 6
// 4754.571 us; speedup vs baseline: 2.7146x; 1.0179x over previous
//
#include <hip/hip_runtime.h>
#include <stdint.h>

#define NROWS  8192
#define DMODEL 768
#define DSAE   24576
#define TOPK   64

// =================== Kernel 1: pre = x @ W_enc + b_enc (fp32) ===================
// R5 structure (single buffer, 2 barriers/K-tile — measured 0 spill, 80% VALU).
// Change vs R5: 8x4 float2 microtile with per-component fmaf -> v_pk_fma_f32
// (2 FMA/issue-slot), and launch_bounds(256,2) so acc+operands (~90 VGPR) fit.
#define BM 128
#define BN 128
#define BK 16
#define APAD 132   // transposed A-store: 2-way write conflict only (free per m136)

__global__ __launch_bounds__(256, 2)
void gemm_enc(const float* __restrict__ x, const float* __restrict__ W,
              const float* __restrict__ bias, float* __restrict__ pre)
{
    __shared__ float As[BK][APAD];   // As[k][m] = x[bm+m][kt+k]
    __shared__ float Bs[BK][BN];     // Bs[k][n] = W[kt+k][bn+n]

    const int tid = threadIdx.x;
    const int bm = blockIdx.y * BM;
    const int bn = blockIdx.x * BN;
    const int ty = tid >> 4;         // 0..15
    const int tx = tid & 15;         // 0..15

    // acc2[i][j]: rows {ty*4+i | 64+ty*4+(i-4)}, col pairs:
    // j=0 -> cols tx*4+0,1   j=1 -> tx*4+2,3   j=2 -> 64+tx*4+0,1   j=3 -> 64+tx*4+2,3
    float2 acc2[8][4];
    #pragma unroll
    for (int i = 0; i < 8; ++i)
        #pragma unroll
        for (int j = 0; j < 4; ++j) acc2[i][j] = make_float2(0.f, 0.f);

    const int am  = tid >> 2;          // A: tile row (l=0), +64 for l=1
    const int akq = (tid & 3) * 4;     // A: k offset (float4 along k)
    const int bk  = tid >> 5;          // B: k row (l=0), +8 for l=1
    const int bnq = (tid & 31) * 4;    // B: n offset (float4 along n)

    for (int kt = 0; kt < DMODEL; kt += BK) {
        #pragma unroll
        for (int l = 0; l < 2; ++l) {
            const int m = am + l * 64;
            float4 av = *(const float4*)(x + (size_t)(bm + m) * DMODEL + kt + akq);
            As[akq + 0][m] = av.x;
            As[akq + 1][m] = av.y;
            As[akq + 2][m] = av.z;
            As[akq + 3][m] = av.w;
            const int k = bk + l * 8;
            *(float4*)(&Bs[k][bnq]) = *(const float4*)(W + (size_t)(kt + k) * DSAE + bn + bnq);
        }
        __syncthreads();
        #pragma unroll
        for (int k = 0; k < BK; ++k) {
            float4 av0 = *(const float4*)(&As[k][ty * 4]);         // rows ty*4..+3
            float4 av1 = *(const float4*)(&As[k][64 + ty * 4]);    // rows 64+ty*4..+3
            float4 bv0 = *(const float4*)(&Bs[k][tx * 4]);         // cols tx*4..+3
            float4 bv1 = *(const float4*)(&Bs[k][64 + tx * 4]);    // cols 64+tx*4..+3
            const float a[8] = {av0.x, av0.y, av0.z, av0.w, av1.x, av1.y, av1.z, av1.w};
            const float2 b2[4] = {make_float2(bv0.x, bv0.y), make_float2(bv0.z, bv0.w),
                                  make_float2(bv1.x, bv1.y), make_float2(bv1.z, bv1.w)};
            #pragma unroll
            for (int i = 0; i < 8; ++i) {
                #pragma unroll
                for (int j = 0; j < 4; ++j) {
                    acc2[i][j].x = fmaf(a[i], b2[j].x, acc2[i][j].x);
                    acc2[i][j].y = fmaf(a[i], b2[j].y, acc2[i][j].y);
                }
            }
        }
        __syncthreads();
    }

    // epilogue: bias + store (rows {ty*4+i, 64+ty*4+i}, cols {tx*4.., 64+tx*4..})
    float4 be0 = *(const float4*)(bias + bn + tx * 4);
    float4 be1 = *(const float4*)(bias + bn + 64 + tx * 4);
    #pragma unroll
    for (int half = 0; half < 2; ++half) {
        #pragma unroll
        for (int i = 0; i < 4; ++i) {
            const int r = bm + half * 64 + ty * 4 + i;
            const int ai = half * 4 + i;
            float* dst = pre + (size_t)r * DSAE + bn;
            *(float4*)(dst + tx * 4) = make_float4(
                acc2[ai][0].x + be0.x, acc2[ai][0].y + be0.y,
                acc2[ai][1].x + be0.z, acc2[ai][1].y + be0.w);
            *(float4*)(dst + 64 + tx * 4) = make_float4(
                acc2[ai][2].x + be1.x, acc2[ai][2].y + be1.y,
                acc2[ai][3].x + be1.z, acc2[ai][3].y + be1.w);
        }
    }
}

// =================== Kernel 2: per-row top-64 select + sparsify + decode ===================
#define NT2 512
#define CAP 4096   // candidate capacity; E[cnt]=1917, sd=42 -> 50 sigma headroom

__device__ __forceinline__ unsigned sortable(float f) {
    unsigned u = __float_as_uint(f);
    return u ^ ((u & 0x80000000u) ? 0xFFFFFFFFu : 0x80000000u);
}

__global__ __launch_bounds__(NT2)
void topk_decode(float* __restrict__ lat, const float* __restrict__ Wd,
                 float* __restrict__ out)
{
    const int row = blockIdx.x;
    const int tid = threadIdx.x;
    float* rowp = lat + (size_t)row * DSAE;

    __shared__ unsigned cand_u[CAP];
    __shared__ int      cand_i[CAP];
    __shared__ int hist[256];
    __shared__ int s_cnt, s_bucket, s_krem, s_total_eq, s_cutoff;
    __shared__ float sel_v[TOPK];
    __shared__ int   sel_j[TOPK];
    __shared__ int   sel_cnt;

    // ---- Phase A: one-pass candidate collection (floor 2.0f = sortable 0xC0000000)
    if (tid == 0) s_cnt = 0;
    __syncthreads();
    for (int i4 = tid; i4 < DSAE / 4; i4 += NT2) {
        float4 v = *(const float4*)(rowp + i4 * 4);
        const float vv[4] = {v.x, v.y, v.z, v.w};
        #pragma unroll
        for (int c = 0; c < 4; ++c) {
            unsigned u = sortable(vv[c]);
            if (u >= 0xC0000000u) {
                int s = atomicAdd(&s_cnt, 1);
                if (s < CAP) { cand_u[s] = u; cand_i[s] = i4 * 4 + c; }
            }
        }
    }
    __syncthreads();
    const int n = s_cnt;
    const bool fast = (n >= TOPK && n <= CAP);

    unsigned T;
    int need_eq, total_eq;

    if (fast) {
        // ---- Phase B (fast): radix-select top-64 among n LDS candidates
        unsigned pbase = 0;
        int k_rem = TOPK;
        #pragma unroll 1
        for (int pass = 0; pass < 4; ++pass) {
            const int shift = 24 - 8 * pass;
            const unsigned mask = pass ? (0xFFFFFFFFu << (32 - 8 * pass)) : 0u;
            if (tid < 256) hist[tid] = 0;
            __syncthreads();
            for (int i = tid; i < n; i += NT2) {
                unsigned u = cand_u[i];
                if ((u & mask) == pbase) atomicAdd(&hist[(u >> shift) & 255], 1);
            }
            __syncthreads();
            if (tid == 0) {
                int acc = 0, b = 255;
                for (; b >= 0; --b) {
                    int h = hist[b];
                    if (acc + h >= k_rem) break;
                    acc += h;
                }
                s_bucket = b;
                s_krem = k_rem - acc;
                s_total_eq = hist[b];
            }
            __syncthreads();
            pbase |= ((unsigned)s_bucket) << shift;
            k_rem = s_krem;
            __syncthreads();
        }
        T = pbase; need_eq = k_rem; total_eq = s_total_eq;
    } else {
        // ---- Phase B (fallback): 4-pass radix over the full global row
        unsigned pbase = 0;
        int k_rem = TOPK;
        #pragma unroll 1
        for (int pass = 0; pass < 4; ++pass) {
            const int shift = 24 - 8 * pass;
            const unsigned mask = pass ? (0xFFFFFFFFu << (32 - 8 * pass)) : 0u;
            if (tid < 256) hist[tid] = 0;
            __syncthreads();
            for (int i = tid; i < DSAE; i += NT2) {
                unsigned u = sortable(rowp[i]);
                if ((u & mask) == pbase) atomicAdd(&hist[(u >> shift) & 255], 1);
            }
            __syncthreads();
            if (tid == 0) {
                int acc = 0, b = 255;
                for (; b >= 0; --b) {
                    int h = hist[b];
                    if (acc + h >= k_rem) break;
                    acc += h;
                }
                s_bucket = b;
                s_krem = k_rem - acc;
                s_total_eq = hist[b];
            }
            __syncthreads();
            pbase |= ((unsigned)s_bucket) << shift;
            k_rem = s_krem;
            __syncthreads();
        }
        T = pbase; need_eq = k_rem; total_eq = s_total_eq;
    }

    // ---- cutoff for exact ties at T (jax.lax.top_k keeps lowest indices)
    if (tid == 0) {
        s_cutoff = DSAE;
        if (total_eq != need_eq) {
            int last = -1;
            for (int r = 0; r < need_eq; ++r) {         // repeated-min (tie path ~never taken)
                int best = DSAE;
                if (fast) {
                    for (int i = 0; i < n; ++i)
                        if (cand_u[i] == T && cand_i[i] > last && cand_i[i] < best) best = cand_i[i];
                } else {
                    for (int i = 0; i < DSAE; ++i)
                        if (sortable(rowp[i]) == T && i > last && i < best) best = i;
                }
                last = best;
            }
            s_cutoff = last;
        }
        sel_cnt = 0;
    }
    __syncthreads();
    const int cutoff = s_cutoff;

    // ---- collect the 64 selected (j, v)
    if (fast) {
        for (int i = tid; i < n; i += NT2) {
            unsigned u = cand_u[i];
            int j = cand_i[i];
            if (u > T || (u == T && j <= cutoff)) {
                int s = atomicAdd(&sel_cnt, 1);
                if (s < TOPK) { sel_j[s] = j; sel_v[s] = rowp[j]; }
            }
        }
    } else {
        for (int i = tid; i < DSAE; i += NT2) {
            float v = rowp[i];
            unsigned u = sortable(v);
            if (u > T || (u == T && i <= cutoff)) {
                int s = atomicAdd(&sel_cnt, 1);
                if (s < TOPK) { sel_j[s] = i; sel_v[s] = v; }
            }
        }
    }
    __syncthreads();

    // ---- zero the row, then scatter the selected values back
    for (int i4 = tid; i4 < DSAE / 4; i4 += NT2)
        *(float4*)(rowp + i4 * 4) = make_float4(0.f, 0.f, 0.f, 0.f);
    __syncthreads();
    if (tid < TOPK) rowp[sel_j[tid]] = sel_v[tid];
    __syncthreads();

    // ---- sparse decode: out[row, :] = sum_s v_s * W_dec[j_s, :]
    float a0 = 0.f, a1 = 0.f;
    #pragma unroll 8
    for (int s = 0; s < TOPK; ++s) {
        const float v = sel_v[s];
        const float* wd = Wd + (size_t)sel_j[s] * DMODEL;
        a0 += v * wd[tid];
        if (tid < 256) a1 += v * wd[512 + tid];
    }
    out[(size_t)row * DMODEL + tid] = a0;
    if (tid < 256) out[(size_t)row * DMODEL + 512 + tid] = a1;
}

// =================== launch ===================
extern "C" void kernel_launch(void* const* d_in, const int* in_sizes, int n_in,
                              void* d_out, int out_size, void* d_ws, size_t ws_size,
                              hipStream_t stream) {
    const float* x     = (const float*)d_in[0];
    const float* W_enc = (const float*)d_in[1];
    const float* b_enc = (const float*)d_in[2];
    const float* W_dec = (const float*)d_in[3];
    float* out = (float*)d_out;
    float* lat = out + (size_t)NROWS * DMODEL;   // latents region of d_out

    dim3 g1(DSAE / BN, NROWS / BM);   // (192, 64)
    gemm_enc<<<g1, 256, 0, stream>>>(x, W_enc, b_enc, lat);
    topk_decode<<<NROWS, NT2, 0, stream>>>(lat, W_dec, out);
}